// Round 5
// baseline (207.393 us; speedup 1.0000x reference)
//
#include <hip/hip_runtime.h>
#include <hip/hip_cooperative_groups.h>
#include <stdint.h>
#include <math.h>

namespace cg = cooperative_groups;

#define NB 16384

// ws_f layout (plain stores each call -> no init/memset needed):
//   ws_f[0..255]  : per-block partial max of ||W1_o||^2
//   ws_f[256]     : max |b1|
//   ws_f[512..543]: action_mean template (32)
//   ws_f[544..575]: action template (32)

// =====================================================================
// Single cooperative kernel, 512 blocks x 256 threads (2 blocks/CU ->
// whole grid co-resident, coop launch provably valid).
// Phase 1: weight stats + honest template chain.  grid.sync().
// Phase 2: 32 rows/block; certified Cauchy-Schwarz bound per row:
//   |c_o| <= ||x||*max||W1_o|| + max|b1| < 16/15  =>  no layer-1 spike
//   =>  row output == template.  Else: exact fp32 fallback inline.
// =====================================================================
__global__ __launch_bounds__(256, 2) void kAll(
    const float* __restrict__ obs, const float* __restrict__ ctx,
    const float* __restrict__ noise,
    const float* __restrict__ W1, const float* __restrict__ b1,
    const float* __restrict__ W2, const float* __restrict__ b2,
    const float* __restrict__ W3, const float* __restrict__ b3,
    const float* __restrict__ Wm, const float* __restrict__ bm,
    float* __restrict__ ws_f, float* __restrict__ out)
{
  cg::grid_group grid = cg::this_grid();
  const int bid = blockIdx.x, tid = threadIdx.x;
  const int wv = tid >> 6, lane = tid & 63;

  __shared__ float pm[4];
  __shared__ unsigned int m2[4][32];
  __shared__ unsigned int F2[4];
  __shared__ float feat[1024];
  __shared__ int fnz;

  // ---------------- phase 1 ----------------
  if (bid < 256) {
    // 4 rows of W1 each -> partial max row-norm^2
    const int r = bid * 4 + wv;
    float ss = 0.f;
    if (lane < 48) {
      float4 v = *(const float4*)(W1 + (size_t)r * 192 + lane * 4);
      ss = v.x * v.x + v.y * v.y + v.z * v.z + v.w * v.w;
    }
    #pragma unroll
    for (int off = 32; off; off >>= 1) ss += __shfl_down(ss, off);
    if (lane == 0) pm[wv] = ss;
    __syncthreads();
    if (tid == 0)
      ws_f[bid] = fmaxf(fmaxf(pm[0], pm[1]), fmaxf(pm[2], pm[3]));
  } else if (bid == 256) {
    float m = 0.f;
    #pragma unroll
    for (int g = 0; g < 4; ++g) m = fmaxf(m, fabsf(b1[tid + 256 * g]));
    #pragma unroll
    for (int off = 32; off; off >>= 1) m = fmaxf(m, __shfl_down(m, off));
    if (lane == 0) pm[wv] = m;
    __syncthreads();
    if (tid == 0)
      ws_f[256] = fmaxf(fmaxf(pm[0], pm[1]), fmaxf(pm[2], pm[3]));
  } else if (bid == 257) {
    // template chain for a (certified) spike-free layer-1 row
    if (tid < 128) ((unsigned int*)m2)[tid] = 0u;
    if (tid == 0) fnz = 0;
    __syncthreads();
    // layer 2 with empty input spikes: c = b2[o]
    #pragma unroll
    for (int g = 0; g < 4; ++g) {
      const int o = tid + 256 * g;
      const float c = b2[o];
      float v = 0.f;
      #pragma unroll
      for (int t = 0; t < 4; ++t) {
        v = v + (c - v) * 0.5f;
        if (v >= 1.0f) { atomicOr(&m2[t][o >> 5], 1u << (o & 31)); v = 0.f; }
      }
    }
    __syncthreads();
    if (tid < 4) {
      unsigned int f = 0;
      #pragma unroll
      for (int w = 0; w < 32; ++w) f |= m2[tid][w];
      F2[tid] = f;
    }
    __syncthreads();
    // layer 3 (honest sparse dot over W3 if any layer-2 spike fired)
    #pragma unroll
    for (int g = 0; g < 4; ++g) {
      const int o = tid + 256 * g;
      const float cb = b3[o];
      float v = 0.f, fs = 0.f;
      #pragma unroll
      for (int t = 0; t < 4; ++t) {
        float c = cb;
        if (F2[t]) {
          for (int wl = 0; wl < 32; ++wl) {
            unsigned int mm = m2[t][wl];
            while (mm) {
              const int k = wl * 32 + __builtin_ctz(mm);
              c += W3[(size_t)o * 1024 + k];
              mm &= (mm - 1);
            }
          }
        }
        v = v + (c - v) * 0.5f;
        if (v >= 1.0f) { fs += 1.0f; v = 0.f; }
      }
      feat[o] = fs * 0.25f;
      if (fs > 0.f) fnz = 1;
    }
    __syncthreads();
    if (tid < 32) {
      float acc = 0.f;
      if (fnz) {  // dot with all-zero feat is exactly 0
        const float* wr = Wm + (size_t)tid * 1024;
        for (int k = 0; k < 1024; ++k) acc += feat[k] * wr[k];
      }
      const float z = acc + bm[tid];
      const float am = tanhf(z);
      const float nz = fminf(fmaxf(noise[tid], -0.1f), 0.1f);
      ws_f[512 + tid] = am;
      ws_f[544 + tid] = am + nz;
    }
  }

  __threadfence();
  grid.sync();

  // ---------------- phase 2 ----------------
  // wave-wide constants (same for all rows)
  float wm2 = fmaxf(fmaxf(ws_f[lane], ws_f[lane + 64]),
                    fmaxf(ws_f[lane + 128], ws_f[lane + 192]));
  #pragma unroll
  for (int off = 32; off; off >>= 1) wm2 = fmaxf(wm2, __shfl_xor(wm2, off));
  const float bmx = ws_f[256];

  for (int i = 0; i < 8; ++i) {
    const int r = bid * 32 + i * 4 + wv;

    // ---- ||x_r||^2 on ALL lanes ----
    float ss = 0.f;
    if (lane < 32) {
      float4 v = ((const float4*)(obs + (size_t)r * 128))[lane];
      ss = v.x * v.x + v.y * v.y + v.z * v.z + v.w * v.w;
    } else if (lane < 48) {
      float4 v = ((const float4*)(ctx + (size_t)r * 64))[lane - 32];
      ss = v.x * v.x + v.y * v.y + v.z * v.z + v.w * v.w;
    }
    #pragma unroll
    for (int off = 32; off; off >>= 1) ss += __shfl_xor(ss, off);

    const float bound = sqrtf(ss) * sqrtf(wm2) * 1.0001f + bmx + 1e-5f;

    if (bound < 1.0666f) {  // < 16/15: no layer-1 spike possible -> template
      if (lane < 8)
        ((float4*)out)[(size_t)r * 8 + lane] =
            ((const float4*)(ws_f + 512))[lane];
      else if (lane < 16)
        ((float4*)(out + (size_t)NB * 32))[(size_t)r * 8 + (lane - 8)] =
            ((const float4*)(ws_f + 544))[lane - 8];
      continue;
    }

    // ============== exact fp32 fallback (whole wave, rare) ==============
    unsigned long long s1b = 0ull;
    for (int g = 0; g < 16; ++g) {
      const int o = lane + 64 * g;
      float c = b1[o];
      const float* w = W1 + (size_t)o * 192;
      for (int k = 0; k < 128; ++k) c += obs[(size_t)r * 128 + k] * w[k];
      for (int k = 0; k < 64; ++k)  c += ctx[(size_t)r * 64 + k] * w[128 + k];
      float v = 0.f;
      #pragma unroll
      for (int t = 0; t < 4; ++t) {
        v = v + (c - v) * 0.5f;
        if (v >= 1.0f) { s1b |= 1ull << (g * 4 + t); v = 0.f; }
      }
    }
    unsigned long long s2b = 0ull;
    for (int g = 0; g < 16; ++g) {
      const int o = lane + 64 * g;
      float v = 0.f;
      for (int t = 0; t < 4; ++t) {
        float c = b2[o];
        for (int ii = 0; ii < 16; ++ii) {
          unsigned long long w = __ballot((s1b >> (ii * 4 + t)) & 1ull);
          while (w) {
            const int k = 64 * ii + __builtin_ctzll(w);
            c += W2[(size_t)o * 1024 + k];
            w &= (w - 1);
          }
        }
        v = v + (c - v) * 0.5f;
        if (v >= 1.0f) { s2b |= 1ull << (g * 4 + t); v = 0.f; }
      }
    }
    float ft[16];
    for (int g = 0; g < 16; ++g) {
      const int o = lane + 64 * g;
      float v = 0.f, fs = 0.f;
      for (int t = 0; t < 4; ++t) {
        float c = b3[o];
        for (int ii = 0; ii < 16; ++ii) {
          unsigned long long w = __ballot((s2b >> (ii * 4 + t)) & 1ull);
          while (w) {
            const int k = 64 * ii + __builtin_ctzll(w);
            c += W3[(size_t)o * 1024 + k];
            w &= (w - 1);
          }
        }
        v = v + (c - v) * 0.5f;
        if (v >= 1.0f) { fs += 1.0f; v = 0.f; }
      }
      ft[g] = fs * 0.25f;
    }
    for (int a = 0; a < 32; ++a) {
      float p = 0.f;
      #pragma unroll
      for (int g = 0; g < 16; ++g)
        p += ft[g] * Wm[(size_t)a * 1024 + lane + 64 * g];
      #pragma unroll
      for (int off = 32; off; off >>= 1) p += __shfl_xor(p, off);
      if (lane == 0) {
        const float z = p + bm[a];
        const float am = tanhf(z);
        const float nz = fminf(fmaxf(noise[a], -0.1f), 0.1f);
        out[(size_t)r * 32 + a] = am;
        out[(size_t)NB * 32 + (size_t)r * 32 + a] = am + nz;
      }
    }
  }
}

// =====================================================================
extern "C" void kernel_launch(void* const* d_in, const int* in_sizes, int n_in,
                              void* d_out, int out_size, void* d_ws, size_t ws_size,
                              hipStream_t stream) {
  const float* obs   = (const float*)d_in[0];
  const float* ctx   = (const float*)d_in[1];
  const float* noise = (const float*)d_in[2];
  const float* W1    = (const float*)d_in[3];
  const float* b1    = (const float*)d_in[4];
  const float* W2    = (const float*)d_in[5];
  const float* b2    = (const float*)d_in[6];
  const float* W3    = (const float*)d_in[7];
  const float* b3    = (const float*)d_in[8];
  const float* Wm    = (const float*)d_in[9];
  const float* bm    = (const float*)d_in[10];
  float* out  = (float*)d_out;
  float* ws_f = (float*)d_ws;

  void* args[13];
  args[0]  = (void*)&obs;  args[1]  = (void*)&ctx;  args[2]  = (void*)&noise;
  args[3]  = (void*)&W1;   args[4]  = (void*)&b1;   args[5]  = (void*)&W2;
  args[6]  = (void*)&b2;   args[7]  = (void*)&W3;   args[8]  = (void*)&b3;
  args[9]  = (void*)&Wm;   args[10] = (void*)&bm;   args[11] = (void*)&ws_f;
  args[12] = (void*)&out;

  hipLaunchCooperativeKernel((const void*)kAll, dim3(512), dim3(256),
                             args, 0, stream);
}

// Round 6
// 92.284 us; speedup vs baseline: 2.2473x; 2.2473x over previous
//
#include <hip/hip_runtime.h>
#include <stdint.h>
#include <math.h>

#define NB 16384

// ws_f layout (all plain stores each call -> no init/memset needed):
//   ws_f[0..255]  : per-block partial max of ||W1_o||^2
//   ws_f[256]     : max |b1|
//   ws_f[512..543]: action_mean template (32)
//   ws_f[544..575]: action template (32)
//
// R5 lesson: do NOT merge these two kernels with hipLaunchCooperativeKernel —
// grid.sync() on gfx950 cost ~100 µs (vs ~4.4 µs for a launch boundary).

// =====================================================================
// kA: weight-derived partial maxima + the downstream template row.
// blocks 0..255 : 4 rows of W1 each -> partial max norm^2 -> ws_f[bid]
// block  256    : max |b1| -> ws_f[256]
// block  257    : template chain for a spike-free layer-1 row:
//                 b2-LIF -> layer3 (honest sparse W3) -> feat mean ->
//                 fnz-guarded Wm dot -> tanh + clipped noise
// =====================================================================
__global__ __launch_bounds__(256) void kA(
    const float* __restrict__ W1, const float* __restrict__ b1,
    const float* __restrict__ b2, const float* __restrict__ b3,
    const float* __restrict__ W3, const float* __restrict__ Wm,
    const float* __restrict__ bm, const float* __restrict__ noise,
    float* __restrict__ ws_f)
{
  const int bid = blockIdx.x, tid = threadIdx.x;
  if (bid < 256) {
    __shared__ float pm[4];
    const int wv = tid >> 6, lane = tid & 63;
    const int r = bid * 4 + wv;
    float ss = 0.f;
    if (lane < 48) {
      float4 v = *(const float4*)(W1 + (size_t)r * 192 + lane * 4);
      ss = v.x * v.x + v.y * v.y + v.z * v.z + v.w * v.w;
    }
    #pragma unroll
    for (int off = 32; off; off >>= 1) ss += __shfl_down(ss, off);
    if (lane == 0) pm[wv] = ss;
    __syncthreads();
    if (tid == 0)
      ws_f[bid] = fmaxf(fmaxf(pm[0], pm[1]), fmaxf(pm[2], pm[3]));
    return;
  }
  if (bid == 256) {
    __shared__ float pm[4];
    const int wv = tid >> 6, lane = tid & 63;
    float m = 0.f;
    #pragma unroll
    for (int g = 0; g < 4; ++g) m = fmaxf(m, fabsf(b1[tid + 256 * g]));
    #pragma unroll
    for (int off = 32; off; off >>= 1) m = fmaxf(m, __shfl_down(m, off));
    if (lane == 0) pm[wv] = m;
    __syncthreads();
    if (tid == 0)
      ws_f[256] = fmaxf(fmaxf(pm[0], pm[1]), fmaxf(pm[2], pm[3]));
    return;
  }
  // ---- template chain (block 257) ----
  __shared__ unsigned int m2[4][32];    // layer-2 output spike bits
  __shared__ unsigned int F2[4];
  __shared__ float feat[1024];
  __shared__ int fnz;
  if (tid < 128) ((unsigned int*)m2)[tid] = 0u;
  if (tid == 0) fnz = 0;
  __syncthreads();
  // layer 2 with (certified) empty input spikes: c = b2[o]
  #pragma unroll
  for (int g = 0; g < 4; ++g) {
    const int o = tid + 256 * g;
    const float c = b2[o];
    float v = 0.f;
    #pragma unroll
    for (int t = 0; t < 4; ++t) {
      v = v + (c - v) * 0.5f;
      if (v >= 1.0f) { atomicOr(&m2[t][o >> 5], 1u << (o & 31)); v = 0.f; }
    }
  }
  __syncthreads();
  if (tid < 4) {
    unsigned int f = 0;
    #pragma unroll
    for (int w = 0; w < 32; ++w) f |= m2[tid][w];
    F2[tid] = f;
  }
  __syncthreads();
  // layer 3 (honest sparse dot over W3 if any layer-2 spike fired)
  #pragma unroll
  for (int g = 0; g < 4; ++g) {
    const int o = tid + 256 * g;
    const float cb = b3[o];
    float v = 0.f, fs = 0.f;
    #pragma unroll
    for (int t = 0; t < 4; ++t) {
      float c = cb;
      if (F2[t]) {
        for (int wl = 0; wl < 32; ++wl) {
          unsigned int mm = m2[t][wl];
          while (mm) {
            const int k = wl * 32 + __builtin_ctz(mm);
            c += W3[(size_t)o * 1024 + k];
            mm &= (mm - 1);
          }
        }
      }
      v = v + (c - v) * 0.5f;
      if (v >= 1.0f) { fs += 1.0f; v = 0.f; }
    }
    feat[o] = fs * 0.25f;
    if (fs > 0.f) fnz = 1;
  }
  __syncthreads();
  if (tid < 32) {
    float acc = 0.f;
    if (fnz) {  // dot with all-zero feat is exactly 0
      const float* wr = Wm + (size_t)tid * 1024;
      for (int k = 0; k < 1024; ++k) acc += feat[k] * wr[k];
    }
    const float z = acc + bm[tid];
    const float am = tanhf(z);
    const float nz = fminf(fmaxf(noise[tid], -0.1f), 0.1f);
    ws_f[512 + tid] = am;
    ws_f[544 + tid] = am + nz;
  }
}

// =====================================================================
// kRow: one wave per batch row. Butterfly-reduce ||x||^2 (all lanes),
// wave-uniform certified bound test:
//   |c_o| <= ||x||*max||W1_o|| + max|b1| < 16/15  =>  no layer-1 spike
//   =>  downstream identical to template  => broadcast template row.
// Otherwise the wave runs the full exact fp32 chain inline (no LDS, no
// __syncthreads -> divergence-safe; ballot-encoded spike masks).
// =====================================================================
__global__ __launch_bounds__(256) void kRow(
    const float* __restrict__ obs, const float* __restrict__ ctx,
    const float* __restrict__ noise,
    const float* __restrict__ W1, const float* __restrict__ b1,
    const float* __restrict__ W2, const float* __restrict__ b2,
    const float* __restrict__ W3, const float* __restrict__ b3,
    const float* __restrict__ Wm, const float* __restrict__ bm,
    const float* __restrict__ ws_f, float* __restrict__ out)
{
  const int tid = threadIdx.x;
  const int wv = tid >> 6, lane = tid & 63;
  const int r = blockIdx.x * 4 + wv;

  // ---- ||x_r||^2, result on ALL lanes ----
  float ss = 0.f;
  if (lane < 32) {
    float4 v = ((const float4*)(obs + (size_t)r * 128))[lane];
    ss = v.x * v.x + v.y * v.y + v.z * v.z + v.w * v.w;
  } else if (lane < 48) {
    float4 v = ((const float4*)(ctx + (size_t)r * 64))[lane - 32];
    ss = v.x * v.x + v.y * v.y + v.z * v.z + v.w * v.w;
  }
  #pragma unroll
  for (int off = 32; off; off >>= 1) ss += __shfl_xor(ss, off);

  // ---- global max of the 256 partial W1-norm maxima (L2-hot) ----
  float wm2 = fmaxf(fmaxf(ws_f[lane], ws_f[lane + 64]),
                    fmaxf(ws_f[lane + 128], ws_f[lane + 192]));
  #pragma unroll
  for (int off = 32; off; off >>= 1) wm2 = fmaxf(wm2, __shfl_xor(wm2, off));
  const float bmx = ws_f[256];

  const float bound = sqrtf(ss) * sqrtf(wm2) * 1.0001f + bmx + 1e-5f;

  if (bound < 1.0666f) {  // < 16/15: no layer-1 spike possible -> template
    if (lane < 8)
      ((float4*)out)[(size_t)r * 8 + lane] = ((const float4*)(ws_f + 512))[lane];
    else if (lane < 16)
      ((float4*)(out + (size_t)NB * 32))[(size_t)r * 8 + (lane - 8)] =
          ((const float4*)(ws_f + 544))[lane - 8];
    return;
  }

  // ================= exact fp32 fallback (whole wave, rare) =============
  // Each lane owns 16 outputs o = lane + 64*g. Spike bits: bit (g*4+t).
  unsigned long long s1b = 0ull;
  for (int g = 0; g < 16; ++g) {
    const int o = lane + 64 * g;
    float c = b1[o];
    const float* w = W1 + (size_t)o * 192;
    for (int k = 0; k < 128; ++k) c += obs[(size_t)r * 128 + k] * w[k];
    for (int k = 0; k < 64; ++k)  c += ctx[(size_t)r * 64 + k] * w[128 + k];
    float v = 0.f;
    #pragma unroll
    for (int t = 0; t < 4; ++t) {
      v = v + (c - v) * 0.5f;
      if (v >= 1.0f) { s1b |= 1ull << (g * 4 + t); v = 0.f; }
    }
  }
  // layer 2: sparse dot over W2 via on-the-fly ballots (uniform exec)
  unsigned long long s2b = 0ull;
  for (int g = 0; g < 16; ++g) {
    const int o = lane + 64 * g;
    float v = 0.f;
    for (int t = 0; t < 4; ++t) {
      float c = b2[o];
      for (int i = 0; i < 16; ++i) {
        unsigned long long w = __ballot((s1b >> (i * 4 + t)) & 1ull);
        while (w) {
          const int k = 64 * i + __builtin_ctzll(w);
          c += W2[(size_t)o * 1024 + k];
          w &= (w - 1);
        }
      }
      v = v + (c - v) * 0.5f;
      if (v >= 1.0f) { s2b |= 1ull << (g * 4 + t); v = 0.f; }
    }
  }
  // layer 3 + mean over t
  float feat[16];
  for (int g = 0; g < 16; ++g) {
    const int o = lane + 64 * g;
    float v = 0.f, fs = 0.f;
    for (int t = 0; t < 4; ++t) {
      float c = b3[o];
      for (int i = 0; i < 16; ++i) {
        unsigned long long w = __ballot((s2b >> (i * 4 + t)) & 1ull);
        while (w) {
          const int k = 64 * i + __builtin_ctzll(w);
          c += W3[(size_t)o * 1024 + k];
          w &= (w - 1);
        }
      }
      v = v + (c - v) * 0.5f;
      if (v >= 1.0f) { fs += 1.0f; v = 0.f; }
    }
    feat[g] = fs * 0.25f;
  }
  // final projection: 32 actions, shuffle-reduced dot
  for (int a = 0; a < 32; ++a) {
    float p = 0.f;
    #pragma unroll
    for (int g = 0; g < 16; ++g)
      p += feat[g] * Wm[(size_t)a * 1024 + lane + 64 * g];
    #pragma unroll
    for (int off = 32; off; off >>= 1) p += __shfl_xor(p, off);
    if (lane == 0) {
      const float z = p + bm[a];
      const float am = tanhf(z);
      const float nz = fminf(fmaxf(noise[a], -0.1f), 0.1f);
      out[(size_t)r * 32 + a] = am;
      out[(size_t)NB * 32 + (size_t)r * 32 + a] = am + nz;
    }
  }
}

// =====================================================================
extern "C" void kernel_launch(void* const* d_in, const int* in_sizes, int n_in,
                              void* d_out, int out_size, void* d_ws, size_t ws_size,
                              hipStream_t stream) {
  const float* obs   = (const float*)d_in[0];
  const float* ctx   = (const float*)d_in[1];
  const float* noise = (const float*)d_in[2];
  const float* W1    = (const float*)d_in[3];
  const float* b1    = (const float*)d_in[4];
  const float* W2    = (const float*)d_in[5];
  const float* b2    = (const float*)d_in[6];
  const float* W3    = (const float*)d_in[7];
  const float* b3    = (const float*)d_in[8];
  const float* Wm    = (const float*)d_in[9];
  const float* bm    = (const float*)d_in[10];
  float* out = (float*)d_out;
  float* ws_f = (float*)d_ws;

  kA<<<258, 256, 0, stream>>>(W1, b1, b2, b3, W3, Wm, bm, noise, ws_f);
  kRow<<<4096, 256, 0, stream>>>(obs, ctx, noise, W1, b1, W2, b2, W3, b3,
                                 Wm, bm, ws_f, out);
}